// Round 1
// baseline (533.132 us; speedup 1.0000x reference)
//
#include <hip/hip_runtime.h>
#include <math.h>

// ---------------------------------------------------------------------------
// NFM forward, split-fp16 MFMA pipeline.
// Pipeline: prep (weight split/transpose) -> per 32K-row chunk:
//   fm_kernel: tmp = 0.5*((x@V)^2 + (x^2)@(V^2)) [split-f16 xv, plain-f16 x2v2]
//              + linear = x@w_wide + b_wide  (fused in staging threads)
//   l1_kernel: h1 = relu(tmp@w1 + b1)        [split-f16]
//   l2_kernel: h2 = relu(h1@w2 + b2)         [split-f16, N padded 85->96]
//   l3_kernel: out = sigmoid(linear + relu(h2@w3+b3)@w_out + b_out)
// All MFMAs: v_mfma_f32_16x16x32_f16 with verified lane layouts:
//   A[m=lane&15][k=(lane>>4)*8+j], B from BT[n][k] rows, D: col=lane&15,
//   row=(lane>>4)*4+reg.
// ---------------------------------------------------------------------------

typedef _Float16 f16;
typedef _Float16 f16x4 __attribute__((ext_vector_type(4)));
typedef _Float16 f16x8 __attribute__((ext_vector_type(8)));
typedef float f32x4 __attribute__((ext_vector_type(4)));

#define B_TOTAL 131072
#define CHUNK   32768
#define NCHUNK  4
#define FDIM    256   // input features (= K of FM GEMMs)
#define KDIM    256   // FM embedding dim (= N of FM GEMMs)
#define D1      128
#define D2      85
#define D2P     96    // padded
#define D3      64

// workspace byte offsets
#define OFF_VT_H   0x0UL        // [256][256] f16
#define OFF_VT_L   0x20000UL
#define OFF_V2T    0x40000UL
#define OFF_W1T_H  0x60000UL    // [128][256] f16
#define OFF_W1T_L  0x70000UL
#define OFF_W2T_H  0x80000UL    // [96][128] f16
#define OFF_W2T_L  0x86000UL
#define OFF_W3T_H  0x8C000UL    // [64][96] f16
#define OFF_W3T_L  0x8F000UL
#define OFF_LINEAR 0x92000UL    // [131072] f32
#define OFF_TMP    0x120000UL   // [32768][256] f32 (per-chunk)
#define OFF_H1     0x2120000UL  // [32768][128] f32
#define OFF_H2     0x3120000UL  // [32768][96]  f32
// end = 0x3D20000 = 64.1 MB needed in d_ws

static __device__ __forceinline__ f32x4 mfma16(f16x8 a, f16x8 b, f32x4 c) {
  return __builtin_amdgcn_mfma_f32_16x16x32_f16(a, b, c, 0, 0, 0);
}

// ---------------------------------------------------------------------------
// prep: split weights to hi/lo f16 transposed [N][K] planes (B-fragments then
// load as contiguous 16B per lane). Pads layer-2 N and layer-3 K to 96 w/ 0.
// ---------------------------------------------------------------------------
__global__ __launch_bounds__(256) void prep_kernel(
    const float* __restrict__ V, const float* __restrict__ w1,
    const float* __restrict__ w2, const float* __restrict__ w3,
    f16* VT_h, f16* VT_l, f16* V2T,
    f16* W1T_h, f16* W1T_l, f16* W2T_h, f16* W2T_l, f16* W3T_h, f16* W3T_l) {
  int idx0 = blockIdx.x * 256 + threadIdx.x;
  int stride = gridDim.x * 256;
  for (int idx = idx0; idx < KDIM * FDIM; idx += stride) {
    int k = idx >> 8, i = idx & 255;          // VT[k][i] = V[i][k]
    float v = V[i * KDIM + k];
    f16 h = (f16)v;
    VT_h[idx] = h;
    VT_l[idx] = (f16)(v - (float)h);
    V2T[idx] = (f16)(v * v);
  }
  for (int idx = idx0; idx < D1 * KDIM; idx += stride) {
    int n = idx >> 8, k = idx & 255;          // W1T[n][k] = w1[k][n]
    float w = w1[k * D1 + n];
    f16 h = (f16)w;
    W1T_h[idx] = h;
    W1T_l[idx] = (f16)(w - (float)h);
  }
  for (int idx = idx0; idx < D2P * D1; idx += stride) {
    int n = idx >> 7, k = idx & 127;          // W2T[n][k], n>=85 -> 0
    float w = (n < D2) ? w2[k * D2 + n] : 0.f;
    f16 h = (f16)w;
    W2T_h[idx] = h;
    W2T_l[idx] = (f16)(w - (float)h);
  }
  for (int idx = idx0; idx < D3 * D2P; idx += stride) {
    int n = idx / D2P, k = idx - n * D2P;     // W3T[n][k], k>=85 -> 0
    float w = (k < D2) ? w3[k * D3 + n] : 0.f;
    f16 h = (f16)w;
    W3T_h[idx] = h;
    W3T_l[idx] = (f16)(w - (float)h);
  }
}

// ---------------------------------------------------------------------------
// fm_kernel: block = 64 rows x 256 cols, K=256 in 8 steps of 32.
// 4 waves; wave w covers n in [w*64, w*64+64) (4 n-tiles), all 4 m-tiles.
// acc: xv[4][4] + x2v2[4][4] f32x4 = 128 VGPR.
// ---------------------------------------------------------------------------
__global__ __launch_bounds__(256) void fm_kernel(
    const float* __restrict__ x, const float* __restrict__ w_wide,
    const float* __restrict__ b_wide,
    const f16* __restrict__ VT_h, const f16* __restrict__ VT_l,
    const f16* __restrict__ V2T, float* __restrict__ tmp,
    float* __restrict__ lin) {
  __shared__ __align__(16) f16 sAh[64 * 40];  // stride 40: 2-way bank alias only
  __shared__ __align__(16) f16 sAl[64 * 40];
  __shared__ __align__(16) f16 sA2[64 * 40];

  const int tid = threadIdx.x;
  const int lane = tid & 63, wv = tid >> 6;
  const int q = lane >> 4, ln = lane & 15;
  const int row0 = blockIdx.x * 64;
  const int sr = tid >> 3, sc = (tid & 7) * 4;  // staging: 8 threads/row, 4 floats each

  f32x4 accV[4][4], acc2[4][4];
#pragma unroll
  for (int i = 0; i < 4; ++i)
#pragma unroll
    for (int j = 0; j < 4; ++j) {
      accV[i][j] = (f32x4){0.f, 0.f, 0.f, 0.f};
      acc2[i][j] = (f32x4){0.f, 0.f, 0.f, 0.f};
    }
  float lin0 = 0.f, lin1 = 0.f;

  for (int ks = 0; ks < 8; ++ks) {
    const int k0 = ks * 32;
    float4 a0 = *(const float4*)(x + (size_t)(row0 + sr) * FDIM + k0 + sc);
    float4 a1 = *(const float4*)(x + (size_t)(row0 + sr + 32) * FDIM + k0 + sc);
    float4 w4 = *(const float4*)(w_wide + k0 + sc);
    lin0 += a0.x * w4.x + a0.y * w4.y + a0.z * w4.z + a0.w * w4.w;
    lin1 += a1.x * w4.x + a1.y * w4.y + a1.z * w4.z + a1.w * w4.w;

    __syncthreads();  // previous iter's frag reads done before overwrite
    {
      float f0[4] = {a0.x, a0.y, a0.z, a0.w};
      float f1[4] = {a1.x, a1.y, a1.z, a1.w};
      f16x4 h0, l0, q0, h1, l1, q1;
#pragma unroll
      for (int j = 0; j < 4; ++j) {
        f16 h = (f16)f0[j];
        h0[j] = h; l0[j] = (f16)(f0[j] - (float)h); q0[j] = (f16)(f0[j] * f0[j]);
        f16 g = (f16)f1[j];
        h1[j] = g; l1[j] = (f16)(f1[j] - (float)g); q1[j] = (f16)(f1[j] * f1[j]);
      }
      int off0 = sr * 40 + sc, off1 = (sr + 32) * 40 + sc;
      *(f16x4*)(sAh + off0) = h0; *(f16x4*)(sAl + off0) = l0; *(f16x4*)(sA2 + off0) = q0;
      *(f16x4*)(sAh + off1) = h1; *(f16x4*)(sAl + off1) = l1; *(f16x4*)(sA2 + off1) = q1;
    }
    __syncthreads();

    f16x8 Ah[4], Al[4], A2[4];
#pragma unroll
    for (int mi = 0; mi < 4; ++mi) {
      int off = (mi * 16 + ln) * 40 + q * 8;
      Ah[mi] = *(const f16x8*)(sAh + off);
      Al[mi] = *(const f16x8*)(sAl + off);
      A2[mi] = *(const f16x8*)(sA2 + off);
    }
#pragma unroll
    for (int ni = 0; ni < 4; ++ni) {
      int n = wv * 64 + ni * 16 + ln;
      size_t boff = (size_t)n * FDIM + k0 + q * 8;
      f16x8 Bh = *(const f16x8*)(VT_h + boff);
      f16x8 Bl = *(const f16x8*)(VT_l + boff);
      f16x8 B2 = *(const f16x8*)(V2T + boff);
#pragma unroll
      for (int mi = 0; mi < 4; ++mi) {
        accV[mi][ni] = mfma16(Al[mi], Bh, accV[mi][ni]);
        accV[mi][ni] = mfma16(Ah[mi], Bl, accV[mi][ni]);
        accV[mi][ni] = mfma16(Ah[mi], Bh, accV[mi][ni]);
        acc2[mi][ni] = mfma16(A2[mi], B2, acc2[mi][ni]);
      }
    }
  }

  // wide/linear part: reduce 8 staging threads per row
  {
    float bw = b_wide[0];
    float s0 = lin0, s1 = lin1;
    s0 += __shfl_xor(s0, 1); s0 += __shfl_xor(s0, 2); s0 += __shfl_xor(s0, 4);
    s1 += __shfl_xor(s1, 1); s1 += __shfl_xor(s1, 2); s1 += __shfl_xor(s1, 4);
    if ((tid & 7) == 0) {
      lin[row0 + sr] = s0 + bw;
      lin[row0 + sr + 32] = s1 + bw;
    }
  }

  // FM epilogue: tmp = 0.5*(xv^2 + x2v2)
#pragma unroll
  for (int mi = 0; mi < 4; ++mi)
#pragma unroll
    for (int ni = 0; ni < 4; ++ni) {
      int n = wv * 64 + ni * 16 + ln;
#pragma unroll
      for (int r = 0; r < 4; ++r) {
        int m = row0 + mi * 16 + q * 4 + r;
        float xv = accV[mi][ni][r];
        tmp[(size_t)m * KDIM + n] = 0.5f * (xv * xv + acc2[mi][ni][r]);
      }
    }
}

// ---------------------------------------------------------------------------
// l1: h1 = relu(tmp@w1 + b1). block = 64 rows x 128 cols, K=256 (8 steps).
// wave w: n in [w*32, w*32+32) (2 n-tiles), all 4 m-tiles.
// ---------------------------------------------------------------------------
__global__ __launch_bounds__(256) void l1_kernel(
    const float* __restrict__ tmp, const f16* __restrict__ W1T_h,
    const f16* __restrict__ W1T_l, const float* __restrict__ b1,
    float* __restrict__ h1) {
  __shared__ __align__(16) f16 sAh[64 * 40];
  __shared__ __align__(16) f16 sAl[64 * 40];
  const int tid = threadIdx.x;
  const int lane = tid & 63, wv = tid >> 6;
  const int q = lane >> 4, ln = lane & 15;
  const int row0 = blockIdx.x * 64;
  const int sr = tid >> 3, sc = (tid & 7) * 4;

  f32x4 acc[4][2];
#pragma unroll
  for (int i = 0; i < 4; ++i) { acc[i][0] = (f32x4){0,0,0,0}; acc[i][1] = (f32x4){0,0,0,0}; }

  for (int ks = 0; ks < 8; ++ks) {
    const int k0 = ks * 32;
    float4 a0 = *(const float4*)(tmp + (size_t)(row0 + sr) * KDIM + k0 + sc);
    float4 a1 = *(const float4*)(tmp + (size_t)(row0 + sr + 32) * KDIM + k0 + sc);
    __syncthreads();
    {
      float f0[4] = {a0.x, a0.y, a0.z, a0.w};
      float f1[4] = {a1.x, a1.y, a1.z, a1.w};
      f16x4 h0, l0, h1v, l1v;
#pragma unroll
      for (int j = 0; j < 4; ++j) {
        f16 h = (f16)f0[j]; h0[j] = h; l0[j] = (f16)(f0[j] - (float)h);
        f16 g = (f16)f1[j]; h1v[j] = g; l1v[j] = (f16)(f1[j] - (float)g);
      }
      int off0 = sr * 40 + sc, off1 = (sr + 32) * 40 + sc;
      *(f16x4*)(sAh + off0) = h0; *(f16x4*)(sAl + off0) = l0;
      *(f16x4*)(sAh + off1) = h1v; *(f16x4*)(sAl + off1) = l1v;
    }
    __syncthreads();

    f16x8 Ah[4], Al[4];
#pragma unroll
    for (int mi = 0; mi < 4; ++mi) {
      int off = (mi * 16 + ln) * 40 + q * 8;
      Ah[mi] = *(const f16x8*)(sAh + off);
      Al[mi] = *(const f16x8*)(sAl + off);
    }
#pragma unroll
    for (int ni = 0; ni < 2; ++ni) {
      int n = wv * 32 + ni * 16 + ln;
      size_t boff = (size_t)n * KDIM + k0 + q * 8;
      f16x8 Bh = *(const f16x8*)(W1T_h + boff);
      f16x8 Bl = *(const f16x8*)(W1T_l + boff);
#pragma unroll
      for (int mi = 0; mi < 4; ++mi) {
        acc[mi][ni] = mfma16(Al[mi], Bh, acc[mi][ni]);
        acc[mi][ni] = mfma16(Ah[mi], Bl, acc[mi][ni]);
        acc[mi][ni] = mfma16(Ah[mi], Bh, acc[mi][ni]);
      }
    }
  }

#pragma unroll
  for (int mi = 0; mi < 4; ++mi)
#pragma unroll
    for (int ni = 0; ni < 2; ++ni) {
      int n = wv * 32 + ni * 16 + ln;
      float bias = b1[n];
#pragma unroll
      for (int r = 0; r < 4; ++r) {
        int m = row0 + mi * 16 + q * 4 + r;
        float z = acc[mi][ni][r] + bias;
        h1[(size_t)m * D1 + n] = z > 0.f ? z : 0.f;
      }
    }
}

// ---------------------------------------------------------------------------
// l2: h2 = relu(h1@w2 + b2), N padded to 96. block = 128 rows x 96 cols,
// K=128 (4 steps). wave w: rows [w*32, w*32+32) (2 m-tiles), all 6 n-tiles.
// ---------------------------------------------------------------------------
__global__ __launch_bounds__(256) void l2_kernel(
    const float* __restrict__ h1, const f16* __restrict__ W2T_h,
    const f16* __restrict__ W2T_l, const float* __restrict__ b2,
    float* __restrict__ h2) {
  __shared__ __align__(16) f16 sAh[128 * 40];
  __shared__ __align__(16) f16 sAl[128 * 40];
  const int tid = threadIdx.x;
  const int lane = tid & 63, wv = tid >> 6;
  const int q = lane >> 4, ln = lane & 15;
  const int row0 = blockIdx.x * 128;
  const int m0w = wv * 32;

  f32x4 acc[2][6];
#pragma unroll
  for (int i = 0; i < 2; ++i)
#pragma unroll
    for (int j = 0; j < 6; ++j) acc[i][j] = (f32x4){0, 0, 0, 0};

  for (int ks = 0; ks < 4; ++ks) {
    const int k0 = ks * 32;
    float4 a[4];
#pragma unroll
    for (int t = 0; t < 4; ++t) {
      int f4 = tid + t * 256;
      int r = f4 >> 3, c = (f4 & 7) * 4;
      a[t] = *(const float4*)(h1 + (size_t)(row0 + r) * D1 + k0 + c);
    }
    __syncthreads();
#pragma unroll
    for (int t = 0; t < 4; ++t) {
      int f4 = tid + t * 256;
      int r = f4 >> 3, c = (f4 & 7) * 4;
      float f0[4] = {a[t].x, a[t].y, a[t].z, a[t].w};
      f16x4 hv, lv;
#pragma unroll
      for (int j = 0; j < 4; ++j) {
        f16 h = (f16)f0[j]; hv[j] = h; lv[j] = (f16)(f0[j] - (float)h);
      }
      int off = r * 40 + c;
      *(f16x4*)(sAh + off) = hv; *(f16x4*)(sAl + off) = lv;
    }
    __syncthreads();

    f16x8 Ah[2], Al[2];
#pragma unroll
    for (int mi = 0; mi < 2; ++mi) {
      int off = (m0w + mi * 16 + ln) * 40 + q * 8;
      Ah[mi] = *(const f16x8*)(sAh + off);
      Al[mi] = *(const f16x8*)(sAl + off);
    }
#pragma unroll
    for (int ni = 0; ni < 6; ++ni) {
      int n = ni * 16 + ln;
      size_t boff = (size_t)n * D1 + k0 + q * 8;
      f16x8 Bh = *(const f16x8*)(W2T_h + boff);
      f16x8 Bl = *(const f16x8*)(W2T_l + boff);
#pragma unroll
      for (int mi = 0; mi < 2; ++mi) {
        acc[mi][ni] = mfma16(Al[mi], Bh, acc[mi][ni]);
        acc[mi][ni] = mfma16(Ah[mi], Bl, acc[mi][ni]);
        acc[mi][ni] = mfma16(Ah[mi], Bh, acc[mi][ni]);
      }
    }
  }

#pragma unroll
  for (int mi = 0; mi < 2; ++mi)
#pragma unroll
    for (int ni = 0; ni < 6; ++ni) {
      int n = ni * 16 + ln;
      float bias = (n < D2) ? b2[n] : 0.f;
#pragma unroll
      for (int r = 0; r < 4; ++r) {
        int m = row0 + m0w + mi * 16 + q * 4 + r;
        float z = acc[mi][ni][r] + bias;
        h2[(size_t)m * D2P + n] = z > 0.f ? z : 0.f;
      }
    }
}

// ---------------------------------------------------------------------------
// l3: h3 = relu(h2@w3 + b3); out = sigmoid(lin + h3@w_out + b_out).
// block = 128 rows x 64 cols, K=96 (3 steps). wave w: rows [w*32,+32).
// Final dot over n=64 via per-lane 4-term partial + 16-lane shfl reduce.
// ---------------------------------------------------------------------------
__global__ __launch_bounds__(256) void l3_kernel(
    const float* __restrict__ h2, const f16* __restrict__ W3T_h,
    const f16* __restrict__ W3T_l, const float* __restrict__ b3,
    const float* __restrict__ w_out, const float* __restrict__ b_out,
    const float* __restrict__ lin, float* __restrict__ out) {
  __shared__ __align__(16) f16 sAh[128 * 40];
  __shared__ __align__(16) f16 sAl[128 * 40];
  const int tid = threadIdx.x;
  const int lane = tid & 63, wv = tid >> 6;
  const int q = lane >> 4, ln = lane & 15;
  const int row0 = blockIdx.x * 128;
  const int m0w = wv * 32;

  f32x4 acc[2][4];
#pragma unroll
  for (int i = 0; i < 2; ++i)
#pragma unroll
    for (int j = 0; j < 4; ++j) acc[i][j] = (f32x4){0, 0, 0, 0};

  for (int ks = 0; ks < 3; ++ks) {
    const int k0 = ks * 32;
    float4 a[4];
#pragma unroll
    for (int t = 0; t < 4; ++t) {
      int f4 = tid + t * 256;
      int r = f4 >> 3, c = (f4 & 7) * 4;
      a[t] = *(const float4*)(h2 + (size_t)(row0 + r) * D2P + k0 + c);
    }
    __syncthreads();
#pragma unroll
    for (int t = 0; t < 4; ++t) {
      int f4 = tid + t * 256;
      int r = f4 >> 3, c = (f4 & 7) * 4;
      float f0[4] = {a[t].x, a[t].y, a[t].z, a[t].w};
      f16x4 hv, lv;
#pragma unroll
      for (int j = 0; j < 4; ++j) {
        f16 h = (f16)f0[j]; hv[j] = h; lv[j] = (f16)(f0[j] - (float)h);
      }
      int off = r * 40 + c;
      *(f16x4*)(sAh + off) = hv; *(f16x4*)(sAl + off) = lv;
    }
    __syncthreads();

    f16x8 Ah[2], Al[2];
#pragma unroll
    for (int mi = 0; mi < 2; ++mi) {
      int off = (m0w + mi * 16 + ln) * 40 + q * 8;
      Ah[mi] = *(const f16x8*)(sAh + off);
      Al[mi] = *(const f16x8*)(sAl + off);
    }
#pragma unroll
    for (int ni = 0; ni < 4; ++ni) {
      int n = ni * 16 + ln;
      size_t boff = (size_t)n * D2P + k0 + q * 8;
      f16x8 Bh = *(const f16x8*)(W3T_h + boff);
      f16x8 Bl = *(const f16x8*)(W3T_l + boff);
#pragma unroll
      for (int mi = 0; mi < 2; ++mi) {
        acc[mi][ni] = mfma16(Al[mi], Bh, acc[mi][ni]);
        acc[mi][ni] = mfma16(Ah[mi], Bl, acc[mi][ni]);
        acc[mi][ni] = mfma16(Ah[mi], Bh, acc[mi][ni]);
      }
    }
  }

  float b3v[4], wov[4];
#pragma unroll
  for (int ni = 0; ni < 4; ++ni) {
    int n = ni * 16 + ln;
    b3v[ni] = b3[n];
    wov[ni] = w_out[n];
  }
  float bo = b_out[0];

#pragma unroll
  for (int mi = 0; mi < 2; ++mi)
#pragma unroll
    for (int r = 0; r < 4; ++r) {
      float part = 0.f;
#pragma unroll
      for (int ni = 0; ni < 4; ++ni) {
        float z = acc[mi][ni][r] + b3v[ni];
        part += (z > 0.f ? z : 0.f) * wov[ni];
      }
      part += __shfl_xor(part, 1);
      part += __shfl_xor(part, 2);
      part += __shfl_xor(part, 4);
      part += __shfl_xor(part, 8);
      if (ln == 0) {
        int m = row0 + m0w + mi * 16 + q * 4 + r;
        float zf = lin[m] + part + bo;
        out[m] = 1.f / (1.f + expf(-zf));
      }
    }
}

// ---------------------------------------------------------------------------
extern "C" void kernel_launch(void* const* d_in, const int* in_sizes, int n_in,
                              void* d_out, int out_size, void* d_ws, size_t ws_size,
                              hipStream_t stream) {
  const float* x = (const float*)d_in[0];
  const float* w_wide = (const float*)d_in[1];
  const float* b_wide = (const float*)d_in[2];
  const float* V = (const float*)d_in[3];
  const float* w1 = (const float*)d_in[4];
  const float* b1 = (const float*)d_in[5];
  const float* w2 = (const float*)d_in[6];
  const float* b2 = (const float*)d_in[7];
  const float* w3 = (const float*)d_in[8];
  const float* b3 = (const float*)d_in[9];
  const float* w_out = (const float*)d_in[10];
  const float* b_out = (const float*)d_in[11];
  float* out = (float*)d_out;
  char* ws = (char*)d_ws;

  f16* VT_h = (f16*)(ws + OFF_VT_H);
  f16* VT_l = (f16*)(ws + OFF_VT_L);
  f16* V2T = (f16*)(ws + OFF_V2T);
  f16* W1T_h = (f16*)(ws + OFF_W1T_H);
  f16* W1T_l = (f16*)(ws + OFF_W1T_L);
  f16* W2T_h = (f16*)(ws + OFF_W2T_H);
  f16* W2T_l = (f16*)(ws + OFF_W2T_L);
  f16* W3T_h = (f16*)(ws + OFF_W3T_H);
  f16* W3T_l = (f16*)(ws + OFF_W3T_L);
  float* lin = (float*)(ws + OFF_LINEAR);
  float* tmp = (float*)(ws + OFF_TMP);
  float* h1 = (float*)(ws + OFF_H1);
  float* h2 = (float*)(ws + OFF_H2);

  prep_kernel<<<64, 256, 0, stream>>>(V, w1, w2, w3, VT_h, VT_l, V2T, W1T_h,
                                      W1T_l, W2T_h, W2T_l, W3T_h, W3T_l);

  for (int c = 0; c < NCHUNK; ++c) {
    const float* x_c = x + (size_t)c * CHUNK * FDIM;
    float* lin_c = lin + (size_t)c * CHUNK;
    float* out_c = out + (size_t)c * CHUNK;
    fm_kernel<<<CHUNK / 64, 256, 0, stream>>>(x_c, w_wide, b_wide, VT_h, VT_l,
                                              V2T, tmp, lin_c);
    l1_kernel<<<CHUNK / 64, 256, 0, stream>>>(tmp, W1T_h, W1T_l, b1, h1);
    l2_kernel<<<CHUNK / 128, 256, 0, stream>>>(h1, W2T_h, W2T_l, b2, h2);
    l3_kernel<<<CHUNK / 128, 256, 0, stream>>>(h2, W3T_h, W3T_l, b3, w_out,
                                               b_out, lin_c, out_c);
  }
}

// Round 2
// 400.066 us; speedup vs baseline: 1.3326x; 1.3326x over previous
//
#include <hip/hip_runtime.h>
#include <math.h>

// ---------------------------------------------------------------------------
// NFM forward, fully-fused split-fp16 MFMA kernel.
//   prep: split/transpose weights into f16 hi/lo planes in d_ws (L2-resident).
//   fused (per 64-row block, 256 thr = 4 waves):
//     FM:  tmp = 0.5*((x@V)^2 + (x^2)@(V^2))  -> LDS hi/lo planes [64][256]
//          lin = x@w_wide + b_wide            -> global ws (tiny)
//     l1:  h1 = relu(tmp@w1+b1)               -> LDS hi/lo [64][128]
//     l2:  h2 = relu(h1@w2+b2)  (N pad 85->96)-> LDS hi/lo [64][96 in s128]
//     l3:  out = sigmoid(lin + relu(h2@w3+b3)@w_out + b_out)
// LDS = exactly 64 KB, regions time-multiplexed:
//   lower 32KB: x-staging (FM loop) -> tmpH (FM epi) -> h2 planes (l2 epi)
//   upper 32KB: tmpL (FM epi)       -> h1 planes (l1 epi)
// Activation planes XOR-swizzled: 16B block b stored at b^(m&7) (h2: stride
// padded to 128 so b^(m&7) stays in range). 2 blocks/CU (LDS-bound).
// MFMA = v_mfma_f32_16x16x32_f16, verified layouts:
//   A[m=lane&15][k=(lane>>4)*8+j]; D: col=lane&15, row=(lane>>4)*4+reg.
// ---------------------------------------------------------------------------

typedef _Float16 f16;
typedef _Float16 f16x4 __attribute__((ext_vector_type(4)));
typedef _Float16 f16x8 __attribute__((ext_vector_type(8)));
typedef float f32x4 __attribute__((ext_vector_type(4)));

#define NROWS   131072
#define ROWS    64      // rows per block
#define FDIM    256
#define KDIM    256
#define D1      128
#define D2      85
#define D2P     96
#define D3      64

// workspace byte offsets (weights + lin only; ~1.1 MB, L2-resident)
#define OFF_VT_H   0x0UL
#define OFF_VT_L   0x20000UL
#define OFF_V2T    0x40000UL
#define OFF_W1T_H  0x60000UL
#define OFF_W1T_L  0x70000UL
#define OFF_W2T_H  0x80000UL
#define OFF_W2T_L  0x86000UL
#define OFF_W3T_H  0x8C000UL
#define OFF_W3T_L  0x8F000UL
#define OFF_LIN    0x92000UL   // [131072] f32

static __device__ __forceinline__ f32x4 mfma16(f16x8 a, f16x8 b, f32x4 c) {
  return __builtin_amdgcn_mfma_f32_16x16x32_f16(a, b, c, 0, 0, 0);
}

// ---------------------------------------------------------------------------
__global__ __launch_bounds__(256) void prep_kernel(
    const float* __restrict__ V, const float* __restrict__ w1,
    const float* __restrict__ w2, const float* __restrict__ w3,
    f16* VT_h, f16* VT_l, f16* V2T,
    f16* W1T_h, f16* W1T_l, f16* W2T_h, f16* W2T_l, f16* W3T_h, f16* W3T_l) {
  int idx0 = blockIdx.x * 256 + threadIdx.x;
  int stride = gridDim.x * 256;
  for (int idx = idx0; idx < KDIM * FDIM; idx += stride) {
    int k = idx >> 8, i = idx & 255;          // VT[k][i] = V[i][k]
    float v = V[i * KDIM + k];
    f16 h = (f16)v;
    VT_h[idx] = h;
    VT_l[idx] = (f16)(v - (float)h);
    V2T[idx] = (f16)(v * v);
  }
  for (int idx = idx0; idx < D1 * KDIM; idx += stride) {
    int n = idx >> 8, k = idx & 255;          // W1T[n][k] = w1[k][n]
    float w = w1[k * D1 + n];
    f16 h = (f16)w;
    W1T_h[idx] = h;
    W1T_l[idx] = (f16)(w - (float)h);
  }
  for (int idx = idx0; idx < D2P * D1; idx += stride) {
    int n = idx >> 7, k = idx & 127;          // W2T[n][k], n>=85 -> 0
    float w = (n < D2) ? w2[k * D2 + n] : 0.f;
    f16 h = (f16)w;
    W2T_h[idx] = h;
    W2T_l[idx] = (f16)(w - (float)h);
  }
  for (int idx = idx0; idx < D3 * D2P; idx += stride) {
    int n = idx / D2P, k = idx - n * D2P;     // W3T[n][k], k>=85 -> 0
    float w = (k < D2) ? w3[k * D3 + n] : 0.f;
    f16 h = (f16)w;
    W3T_h[idx] = h;
    W3T_l[idx] = (f16)(w - (float)h);
  }
}

// ---------------------------------------------------------------------------
__global__ __launch_bounds__(256, 2) void fused_kernel(
    const float* __restrict__ x, const float* __restrict__ w_wide,
    const float* __restrict__ b_wide,
    const f16* __restrict__ VT_h, const f16* __restrict__ VT_l,
    const f16* __restrict__ V2T,
    const f16* __restrict__ W1T_h, const f16* __restrict__ W1T_l,
    const float* __restrict__ b1,
    const f16* __restrict__ W2T_h, const f16* __restrict__ W2T_l,
    const float* __restrict__ b2,
    const f16* __restrict__ W3T_h, const f16* __restrict__ W3T_l,
    const float* __restrict__ b3,
    const float* __restrict__ w_out, const float* __restrict__ b_out,
    float* __restrict__ lin_g, float* __restrict__ out) {
  __shared__ __align__(16) f16 smem[32768];  // exactly 64 KB

  // region aliases (f16 element offsets); temporally disjoint uses
  f16* tmpH = smem;            // [64][256] swizzled   (FM epi .. l1 loop)
  f16* tmpL = smem + 16384;    // [64][256] swizzled
  f16* sXh  = smem;            // [64][40] padded      (FM loop only)
  f16* sXl  = smem + 2560;
  f16* sX2  = smem + 5120;
  f16* h1H  = smem + 16384;    // [64][128] swizzled   (l1 epi .. l2 loop)
  f16* h1L  = smem + 24576;
  f16* h2H  = smem;            // [64][96 in stride128] (l2 epi .. l3 loop)
  f16* h2L  = smem + 8192;

  const int tid = threadIdx.x;
  const int lane = tid & 63, wv = tid >> 6;
  const int q = lane >> 4, ln = lane & 15;
  const int row0 = blockIdx.x * ROWS;
  const int sr = tid >> 3, sc = (tid & 7) * 4;  // staging: 8 thr/row, 4 floats

  // ---------------- FM stage ----------------
  f32x4 accV[4][4], acc2[4][4];
#pragma unroll
  for (int i = 0; i < 4; ++i)
#pragma unroll
    for (int j = 0; j < 4; ++j) {
      accV[i][j] = (f32x4){0.f, 0.f, 0.f, 0.f};
      acc2[i][j] = (f32x4){0.f, 0.f, 0.f, 0.f};
    }
  float lin0 = 0.f, lin1 = 0.f;

  for (int ks = 0; ks < 8; ++ks) {
    const int k0 = ks * 32;
    float4 a0 = *(const float4*)(x + (size_t)(row0 + sr) * FDIM + k0 + sc);
    float4 a1 = *(const float4*)(x + (size_t)(row0 + sr + 32) * FDIM + k0 + sc);
    float4 w4 = *(const float4*)(w_wide + k0 + sc);
    lin0 += a0.x * w4.x + a0.y * w4.y + a0.z * w4.z + a0.w * w4.w;
    lin1 += a1.x * w4.x + a1.y * w4.y + a1.z * w4.z + a1.w * w4.w;

    __syncthreads();  // previous iter's frag reads done before overwrite
    {
      float f0[4] = {a0.x, a0.y, a0.z, a0.w};
      float f1[4] = {a1.x, a1.y, a1.z, a1.w};
      f16x4 h0, l0, q0, h1v, l1v, q1v;
#pragma unroll
      for (int j = 0; j < 4; ++j) {
        f16 h = (f16)f0[j];
        h0[j] = h; l0[j] = (f16)(f0[j] - (float)h); q0[j] = (f16)(f0[j] * f0[j]);
        f16 g = (f16)f1[j];
        h1v[j] = g; l1v[j] = (f16)(f1[j] - (float)g); q1v[j] = (f16)(f1[j] * f1[j]);
      }
      int off0 = sr * 40 + sc, off1 = (sr + 32) * 40 + sc;
      *(f16x4*)(sXh + off0) = h0; *(f16x4*)(sXl + off0) = l0; *(f16x4*)(sX2 + off0) = q0;
      *(f16x4*)(sXh + off1) = h1v; *(f16x4*)(sXl + off1) = l1v; *(f16x4*)(sX2 + off1) = q1v;
    }
    __syncthreads();

    f16x8 Ah[4], Al[4], A2[4];
#pragma unroll
    for (int mi = 0; mi < 4; ++mi) {
      int off = (mi * 16 + ln) * 40 + q * 8;
      Ah[mi] = *(const f16x8*)(sXh + off);
      Al[mi] = *(const f16x8*)(sXl + off);
      A2[mi] = *(const f16x8*)(sX2 + off);
    }
#pragma unroll
    for (int ni = 0; ni < 4; ++ni) {
      int n = wv * 64 + ni * 16 + ln;
      size_t boff = (size_t)n * FDIM + k0 + q * 8;
      f16x8 Bh = *(const f16x8*)(VT_h + boff);
      f16x8 Bl = *(const f16x8*)(VT_l + boff);
      f16x8 B2 = *(const f16x8*)(V2T + boff);
#pragma unroll
      for (int mi = 0; mi < 4; ++mi) {
        accV[mi][ni] = mfma16(Al[mi], Bh, accV[mi][ni]);
        accV[mi][ni] = mfma16(Ah[mi], Bl, accV[mi][ni]);
        accV[mi][ni] = mfma16(Ah[mi], Bh, accV[mi][ni]);
        acc2[mi][ni] = mfma16(A2[mi], B2, acc2[mi][ni]);
      }
    }
  }

  // wide/linear part -> global ws
  {
    float bw = b_wide[0];
    float s0 = lin0, s1 = lin1;
    s0 += __shfl_xor(s0, 1); s0 += __shfl_xor(s0, 2); s0 += __shfl_xor(s0, 4);
    s1 += __shfl_xor(s1, 1); s1 += __shfl_xor(s1, 2); s1 += __shfl_xor(s1, 4);
    if ((tid & 7) == 0) {
      lin_g[row0 + sr] = s0 + bw;
      lin_g[row0 + sr + 32] = s1 + bw;
    }
  }

  __syncthreads();  // all frag reads done; staging region may be overwritten

  // FM epilogue: tmp = 0.5*(xv^2 + x2v2) -> LDS hi/lo, swizzled [m][256]
#pragma unroll
  for (int mi = 0; mi < 4; ++mi)
#pragma unroll
    for (int r = 0; r < 4; ++r) {
      int m = mi * 16 + q * 4 + r;
      int mrow = m * 256, msw = m & 7;
#pragma unroll
      for (int ni = 0; ni < 4; ++ni) {
        int n = wv * 64 + ni * 16 + ln;
        float xv = accV[mi][ni][r];
        float val = 0.5f * (xv * xv + acc2[mi][ni][r]);
        f16 hi = (f16)val;
        f16 lo = (f16)(val - (float)hi);
        int off = mrow + (((n >> 3) ^ msw) << 3) + (n & 7);
        tmpH[off] = hi;
        tmpL[off] = lo;
      }
    }

  __syncthreads();

  // ---------------- l1: h1 = relu(tmp@w1+b1), N=128, K=256 ----------------
  f32x4 acc1[4][2];
#pragma unroll
  for (int i = 0; i < 4; ++i) { acc1[i][0] = (f32x4){0,0,0,0}; acc1[i][1] = (f32x4){0,0,0,0}; }

#pragma unroll
  for (int ks = 0; ks < 8; ++ks) {
    f16x8 Ah[4], Al[4];
#pragma unroll
    for (int mi = 0; mi < 4; ++mi) {
      int m = mi * 16 + ln;
      int off = m * 256 + (((ks * 4 + q) ^ (m & 7)) << 3);
      Ah[mi] = *(const f16x8*)(tmpH + off);
      Al[mi] = *(const f16x8*)(tmpL + off);
    }
#pragma unroll
    for (int ni = 0; ni < 2; ++ni) {
      int n = wv * 32 + ni * 16 + ln;
      size_t boff = (size_t)n * KDIM + ks * 32 + q * 8;
      f16x8 Bh = *(const f16x8*)(W1T_h + boff);
      f16x8 Bl = *(const f16x8*)(W1T_l + boff);
#pragma unroll
      for (int mi = 0; mi < 4; ++mi) {
        acc1[mi][ni] = mfma16(Al[mi], Bh, acc1[mi][ni]);
        acc1[mi][ni] = mfma16(Ah[mi], Bl, acc1[mi][ni]);
        acc1[mi][ni] = mfma16(Ah[mi], Bh, acc1[mi][ni]);
      }
    }
  }

  __syncthreads();  // tmp reads done; upper half may be overwritten

  // l1 epilogue -> h1 planes (upper half), swizzled [m][128]
#pragma unroll
  for (int mi = 0; mi < 4; ++mi)
#pragma unroll
    for (int r = 0; r < 4; ++r) {
      int m = mi * 16 + q * 4 + r;
      int mrow = m * 128, msw = m & 7;
#pragma unroll
      for (int ni = 0; ni < 2; ++ni) {
        int n = wv * 32 + ni * 16 + ln;
        float z = acc1[mi][ni][r] + b1[n];
        z = z > 0.f ? z : 0.f;
        f16 hi = (f16)z;
        f16 lo = (f16)(z - (float)hi);
        int off = mrow + (((n >> 3) ^ msw) << 3) + (n & 7);
        h1H[off] = hi;
        h1L[off] = lo;
      }
    }

  __syncthreads();

  // ---------------- l2: h2 = relu(h1@w2+b2), N=96(pad), K=128 --------------
  // wave wv handles m-tile wv (16 rows), all 6 n-tiles
  f32x4 accL2[6];
#pragma unroll
  for (int j = 0; j < 6; ++j) accL2[j] = (f32x4){0, 0, 0, 0};

#pragma unroll
  for (int ks = 0; ks < 4; ++ks) {
    int m = wv * 16 + ln;
    int aoff = m * 128 + (((ks * 4 + q) ^ (m & 7)) << 3);
    f16x8 Ah = *(const f16x8*)(h1H + aoff);
    f16x8 Al = *(const f16x8*)(h1L + aoff);
#pragma unroll
    for (int ni = 0; ni < 6; ++ni) {
      int n = ni * 16 + ln;
      size_t boff = (size_t)n * D1 + ks * 32 + q * 8;
      f16x8 Bh = *(const f16x8*)(W2T_h + boff);
      f16x8 Bl = *(const f16x8*)(W2T_l + boff);
      accL2[ni] = mfma16(Al, Bh, accL2[ni]);
      accL2[ni] = mfma16(Ah, Bl, accL2[ni]);
      accL2[ni] = mfma16(Ah, Bh, accL2[ni]);
    }
  }

  // l2 epilogue -> h2 planes (lower half, disjoint from h1 upper): no barrier
#pragma unroll
  for (int r = 0; r < 4; ++r) {
    int m = wv * 16 + q * 4 + r;
    int mrow = m * 128, msw = m & 7;
#pragma unroll
    for (int ni = 0; ni < 6; ++ni) {
      int n = ni * 16 + ln;
      float z = accL2[ni][r] + ((n < D2) ? b2[n] : 0.f);
      z = z > 0.f ? z : 0.f;
      f16 hi = (f16)z;
      f16 lo = (f16)(z - (float)hi);
      int off = mrow + (((n >> 3) ^ msw) << 3) + (n & 7);
      h2H[off] = hi;
      h2L[off] = lo;
    }
  }

  __syncthreads();

  // ---------------- l3 + out: K=96, N=64 ----------------
  f32x4 accL3[4];
#pragma unroll
  for (int j = 0; j < 4; ++j) accL3[j] = (f32x4){0, 0, 0, 0};

#pragma unroll
  for (int ks = 0; ks < 3; ++ks) {
    int m = wv * 16 + ln;
    int aoff = m * 128 + (((ks * 4 + q) ^ (m & 7)) << 3);
    f16x8 Ah = *(const f16x8*)(h2H + aoff);
    f16x8 Al = *(const f16x8*)(h2L + aoff);
#pragma unroll
    for (int ni = 0; ni < 4; ++ni) {
      int n = ni * 16 + ln;
      size_t boff = (size_t)n * D2P + ks * 32 + q * 8;
      f16x8 Bh = *(const f16x8*)(W3T_h + boff);
      f16x8 Bl = *(const f16x8*)(W3T_l + boff);
      accL3[ni] = mfma16(Al, Bh, accL3[ni]);
      accL3[ni] = mfma16(Ah, Bl, accL3[ni]);
      accL3[ni] = mfma16(Ah, Bh, accL3[ni]);
    }
  }

  {
    float b3v[4], wov[4];
#pragma unroll
    for (int ni = 0; ni < 4; ++ni) {
      int n = ni * 16 + ln;
      b3v[ni] = b3[n];
      wov[ni] = w_out[n];
    }
    float bo = b_out[0];
#pragma unroll
    for (int r = 0; r < 4; ++r) {
      float part = 0.f;
#pragma unroll
      for (int ni = 0; ni < 4; ++ni) {
        float z = accL3[ni][r] + b3v[ni];
        part += (z > 0.f ? z : 0.f) * wov[ni];
      }
      part += __shfl_xor(part, 1);
      part += __shfl_xor(part, 2);
      part += __shfl_xor(part, 4);
      part += __shfl_xor(part, 8);
      if (ln == 0) {
        int m = row0 + wv * 16 + q * 4 + r;
        float lv = *((volatile const float*)(lin_g + m));  // bypass L1
        float zf = lv + part + bo;
        out[m] = 1.f / (1.f + expf(-zf));
      }
    }
  }
}

// ---------------------------------------------------------------------------
extern "C" void kernel_launch(void* const* d_in, const int* in_sizes, int n_in,
                              void* d_out, int out_size, void* d_ws, size_t ws_size,
                              hipStream_t stream) {
  const float* x = (const float*)d_in[0];
  const float* w_wide = (const float*)d_in[1];
  const float* b_wide = (const float*)d_in[2];
  const float* V = (const float*)d_in[3];
  const float* w1 = (const float*)d_in[4];
  const float* b1 = (const float*)d_in[5];
  const float* w2 = (const float*)d_in[6];
  const float* b2 = (const float*)d_in[7];
  const float* w3 = (const float*)d_in[8];
  const float* b3 = (const float*)d_in[9];
  const float* w_out = (const float*)d_in[10];
  const float* b_out = (const float*)d_in[11];
  float* out = (float*)d_out;
  char* ws = (char*)d_ws;

  f16* VT_h = (f16*)(ws + OFF_VT_H);
  f16* VT_l = (f16*)(ws + OFF_VT_L);
  f16* V2T = (f16*)(ws + OFF_V2T);
  f16* W1T_h = (f16*)(ws + OFF_W1T_H);
  f16* W1T_l = (f16*)(ws + OFF_W1T_L);
  f16* W2T_h = (f16*)(ws + OFF_W2T_H);
  f16* W2T_l = (f16*)(ws + OFF_W2T_L);
  f16* W3T_h = (f16*)(ws + OFF_W3T_H);
  f16* W3T_l = (f16*)(ws + OFF_W3T_L);
  float* lin_g = (float*)(ws + OFF_LIN);

  prep_kernel<<<64, 256, 0, stream>>>(V, w1, w2, w3, VT_h, VT_l, V2T, W1T_h,
                                      W1T_l, W2T_h, W2T_l, W3T_h, W3T_l);

  fused_kernel<<<NROWS / ROWS, 256, 0, stream>>>(
      x, w_wide, b_wide, VT_h, VT_l, V2T, W1T_h, W1T_l, b1, W2T_h, W2T_l, b2,
      W3T_h, W3T_l, b3, w_out, b_out, lin_g, out);
}